// Round 1
// baseline (16895.094 us; speedup 1.0000x reference)
//
#include <hip/hip_runtime.h>
#include <cstddef>
#include <cmath>

// ---------------- constants ----------------
#define Bc   2
#define Lc   512
#define Dc   768
#define NLc  24
#define NSc  16
#define Kc   4
#define DIc  1536
#define Rc   48
#define Hc   200
#define D2c  800
#define DI2c 1600
#define R2c  50

__device__ __forceinline__ float sigmoidf_(float x) { return 1.f / (1.f + expf(-x)); }
__device__ __forceinline__ float siluf_(float x)    { return x / (1.f + expf(-x)); }
__device__ __forceinline__ float softplusf_(float x) {
    return x > 0.f ? x + log1pf(expf(-x)) : log1pf(expf(x));
}

// ---------------- embedding lookup ----------------
__global__ void embed_kernel(const int* __restrict__ ids, const float* __restrict__ emb,
                             float* __restrict__ h, int total, int Dd) {
    int idx = blockIdx.x * blockDim.x + threadIdx.x;
    if (idx >= total) return;
    int d = idx % Dd;
    int t = idx / Dd;
    h[idx] = emb[(size_t)ids[t] * Dd + d];
}

// ---------------- rmsnorm (one block per row) ----------------
__global__ __launch_bounds__(256) void rmsnorm_kernel(const float* __restrict__ x,
                                                      const float* __restrict__ w,
                                                      float* __restrict__ out, int Dd) {
    int row = blockIdx.x;
    const float* xr = x + (size_t)row * Dd;
    float* orow = out + (size_t)row * Dd;
    float ss = 0.f;
    for (int d = threadIdx.x; d < Dd; d += 256) { float v = xr[d]; ss += v * v; }
    for (int off = 32; off > 0; off >>= 1) ss += __shfl_down(ss, off);
    __shared__ float sw[4];
    __shared__ float sinv;
    if ((threadIdx.x & 63) == 0) sw[threadIdx.x >> 6] = ss;
    __syncthreads();
    if (threadIdx.x == 0) sinv = rsqrtf((sw[0] + sw[1] + sw[2] + sw[3]) / (float)Dd + 1e-5f);
    __syncthreads();
    float inv = sinv;
    for (int d = threadIdx.x; d < Dd; d += 256) orow[d] = xr[d] * inv * w[d];
}

// ---------------- tiled fp32 GEMM:  C[m,n] = sum_k X[m,k]*W[n,k]  ----------------
// EPI: 0 = plain store, 1 = softplus(acc + bias[n]), 2 = residual add (C += acc)
template <int EPI>
__global__ __launch_bounds__(256) void gemm_nt(const float* __restrict__ X, int lda,
                                               const float* __restrict__ W, int ldw,
                                               float* __restrict__ C, int ldc,
                                               int M, int N, int Kd,
                                               const float* __restrict__ bias) {
    const int BM = 64, BN = 64, BK = 16;
    __shared__ float As[BK][BM + 4];
    __shared__ float Bs[BK][BN + 4];
    int tid = threadIdx.x;
    int bm = blockIdx.y * BM;
    int bn = blockIdx.x * BN;
    int tm = (tid >> 4) << 2;
    int tn = (tid & 15) << 2;
    float acc[4][4];
#pragma unroll
    for (int i = 0; i < 4; i++)
#pragma unroll
        for (int j = 0; j < 4; j++) acc[i][j] = 0.f;

    int lr = tid >> 2;         // 0..63
    int lc = (tid & 3) << 2;   // 0,4,8,12

    for (int k0 = 0; k0 < Kd; k0 += BK) {
        // X tile -> As[k][m]
        {
            int row = bm + lr;
            float4 v = make_float4(0.f, 0.f, 0.f, 0.f);
            if (row < M) {
                if (k0 + BK <= Kd) {
                    v = *(const float4*)(X + (size_t)row * lda + k0 + lc);
                } else {
                    float t0 = 0.f, t1 = 0.f, t2 = 0.f, t3 = 0.f;
                    if (k0 + lc + 0 < Kd) t0 = X[(size_t)row * lda + k0 + lc + 0];
                    if (k0 + lc + 1 < Kd) t1 = X[(size_t)row * lda + k0 + lc + 1];
                    if (k0 + lc + 2 < Kd) t2 = X[(size_t)row * lda + k0 + lc + 2];
                    if (k0 + lc + 3 < Kd) t3 = X[(size_t)row * lda + k0 + lc + 3];
                    v = make_float4(t0, t1, t2, t3);
                }
            }
            As[lc + 0][lr] = v.x; As[lc + 1][lr] = v.y;
            As[lc + 2][lr] = v.z; As[lc + 3][lr] = v.w;
        }
        // W tile -> Bs[k][n]
        {
            int row = bn + lr;
            float4 v = make_float4(0.f, 0.f, 0.f, 0.f);
            if (row < N) {
                if (k0 + BK <= Kd) {
                    v = *(const float4*)(W + (size_t)row * ldw + k0 + lc);
                } else {
                    float t0 = 0.f, t1 = 0.f, t2 = 0.f, t3 = 0.f;
                    if (k0 + lc + 0 < Kd) t0 = W[(size_t)row * ldw + k0 + lc + 0];
                    if (k0 + lc + 1 < Kd) t1 = W[(size_t)row * ldw + k0 + lc + 1];
                    if (k0 + lc + 2 < Kd) t2 = W[(size_t)row * ldw + k0 + lc + 2];
                    if (k0 + lc + 3 < Kd) t3 = W[(size_t)row * ldw + k0 + lc + 3];
                    v = make_float4(t0, t1, t2, t3);
                }
            }
            Bs[lc + 0][lr] = v.x; Bs[lc + 1][lr] = v.y;
            Bs[lc + 2][lr] = v.z; Bs[lc + 3][lr] = v.w;
        }
        __syncthreads();
#pragma unroll
        for (int k = 0; k < BK; k++) {
            float a0 = As[k][tm + 0], a1 = As[k][tm + 1], a2 = As[k][tm + 2], a3 = As[k][tm + 3];
            float b0 = Bs[k][tn + 0], b1 = Bs[k][tn + 1], b2 = Bs[k][tn + 2], b3 = Bs[k][tn + 3];
            acc[0][0] += a0 * b0; acc[0][1] += a0 * b1; acc[0][2] += a0 * b2; acc[0][3] += a0 * b3;
            acc[1][0] += a1 * b0; acc[1][1] += a1 * b1; acc[1][2] += a1 * b2; acc[1][3] += a1 * b3;
            acc[2][0] += a2 * b0; acc[2][1] += a2 * b1; acc[2][2] += a2 * b2; acc[2][3] += a2 * b3;
            acc[3][0] += a3 * b0; acc[3][1] += a3 * b1; acc[3][2] += a3 * b2; acc[3][3] += a3 * b3;
        }
        __syncthreads();
    }
#pragma unroll
    for (int i = 0; i < 4; i++) {
        int m = bm + tm + i;
        if (m >= M) continue;
#pragma unroll
        for (int j = 0; j < 4; j++) {
            int n = bn + tn + j;
            if (n >= N) continue;
            float v = acc[i][j];
            if (EPI == 1) v = softplusf_(v + bias[n]);
            if (EPI == 2) v += C[(size_t)m * ldc + n];
            C[(size_t)m * ldc + n] = v;
        }
    }
}

// ---------------- causal conv (K=4) + SiLU ----------------
__global__ void conv_silu_kernel(const float* __restrict__ xz, const float* __restrict__ cw,
                                 const float* __restrict__ cb, float* __restrict__ u,
                                 int total) {
    int idx = blockIdx.x * blockDim.x + threadIdx.x;
    if (idx >= total) return;
    int c = idx % DIc;
    int l = (idx / DIc) % Lc;
    int b = idx / (DIc * Lc);
    float acc = cb[c];
#pragma unroll
    for (int k = 0; k < Kc; k++) {
        int ls = l - (Kc - 1) + k;
        if (ls >= 0) acc += xz[((size_t)(b * Lc + ls)) * (2 * DIc) + c] * cw[c * Kc + k];
    }
    u[idx] = siluf_(acc);
}

// ---------------- selective scan: thread per (b,d,n) ----------------
__global__ __launch_bounds__(256) void scan_kernel(const float* __restrict__ dt,
                                                   const float* __restrict__ u,
                                                   const float* __restrict__ dbl,
                                                   const float* __restrict__ A_log,
                                                   const float* __restrict__ Dp,
                                                   float* __restrict__ y) {
    int gid = blockIdx.x * blockDim.x + threadIdx.x;
    int n = gid & 15;
    int d = (gid >> 4) % DIc;
    int b = gid / (16 * DIc);
    float A  = -expf(A_log[d * NSc + n]);
    float Dv = Dp[d];
    float h = 0.f;
    const float* dtp = dt + (size_t)b * Lc * DIc + d;
    const float* up  = u + (size_t)b * Lc * DIc + d;
    const float* blp = dbl + (size_t)b * Lc * 80 + Rc + n;  // B at +0, C at +16
    float* yp = y + (size_t)b * Lc * DIc + d;

    float dtv = dtp[0], uv = up[0], Bv = blp[0], Cv = blp[16];
    for (int l = 0; l < Lc; l++) {
        float dtn = 0.f, un = 0.f, Bn2 = 0.f, Cn = 0.f;
        if (l + 1 < Lc) {
            size_t o = (size_t)(l + 1) * DIc;
            dtn = dtp[o]; un = up[o];
            size_t ob = (size_t)(l + 1) * 80;
            Bn2 = blp[ob]; Cn = blp[ob + 16];
        }
        float dA = expf(dtv * A);
        h = dA * h + dtv * Bv * uv;
        float p = h * Cv;
        p += __shfl_xor(p, 1);
        p += __shfl_xor(p, 2);
        p += __shfl_xor(p, 4);
        p += __shfl_xor(p, 8);
        if (n == 0) yp[(size_t)l * DIc] = p + Dv * uv;
        dtv = dtn; uv = un; Bv = Bn2; Cv = Cn;
    }
}

// ---------------- y *= silu(z) ----------------
__global__ void zmul_kernel(float* __restrict__ y, const float* __restrict__ xz, int total) {
    int idx = blockIdx.x * blockDim.x + threadIdx.x;
    if (idx >= total) return;
    int c = idx % DIc;
    int bl = idx / DIc;
    float z = xz[(size_t)bl * (2 * DIc) + DIc + c];
    y[idx] *= siluf_(z);
}

// ---------------- masked mean pool ----------------
__global__ void pool_kernel(const float* __restrict__ xn, const int* __restrict__ mask,
                            float* __restrict__ pooled, int total) {
    int idx = blockIdx.x * blockDim.x + threadIdx.x;
    if (idx >= total) return;
    int b = idx / Dc;
    int d = idx % Dc;
    float s = 0.f, ms = 0.f;
    for (int l = 0; l < Lc; l++) {
        float m = (float)mask[b * Lc + l];
        s += xn[((size_t)(b * Lc + l)) * Dc + d] * m;
        ms += m;
    }
    pooled[idx] = s / ms;
}

// ---------------- LSTM cell (one block per batch element) ----------------
__global__ __launch_bounds__(256) void lstm_cell_kernel(const float* __restrict__ x, int xdim,
                                                        const float* __restrict__ h0,
                                                        const float* __restrict__ c0,
                                                        const float* __restrict__ Wih,
                                                        const float* __restrict__ Whh,
                                                        const float* __restrict__ bih,
                                                        const float* __restrict__ bhh,
                                                        float* __restrict__ h_out,
                                                        float* __restrict__ c_out) {
    __shared__ float g[4 * Hc];
    int b = blockIdx.x;
    int tid = threadIdx.x;
    const float* xb = x + (size_t)b * xdim;
    for (int j = tid; j < 4 * Hc; j += 256) {
        float acc = bih[j] + bhh[j];
        const float* wr = Wih + (size_t)j * xdim;
        for (int k = 0; k < xdim; k++) acc += xb[k] * wr[k];
        if (h0) {
            const float* hr = Whh + (size_t)j * Hc;
            const float* hb = h0 + (size_t)b * Hc;
            for (int k = 0; k < Hc; k++) acc += hb[k] * hr[k];
        }
        g[j] = acc;
    }
    __syncthreads();
    for (int j = tid; j < Hc; j += 256) {
        float ig = sigmoidf_(g[j]);
        float fg = sigmoidf_(g[Hc + j]);
        float gg = tanhf(g[2 * Hc + j]);
        float og = sigmoidf_(g[3 * Hc + j]);
        float cprev = c0 ? c0[(size_t)b * Hc + j] : 0.f;
        float c = fg * cprev + ig * gg;
        h_out[(size_t)b * Hc + j] = og * tanhf(c);
        if (c_out) c_out[(size_t)b * Hc + j] = c;
    }
}

// ---------------- concat [h1f | hf2 | h1b | hb2] -> (B, 800) ----------------
__global__ void concat_kernel(const float* __restrict__ h1f, const float* __restrict__ hf2,
                              const float* __restrict__ h1b, const float* __restrict__ hb2,
                              float* __restrict__ x2, int total) {
    int idx = blockIdx.x * blockDim.x + threadIdx.x;
    if (idx >= total) return;
    int b = idx / (4 * Hc);
    int j = idx % (4 * Hc);
    const float* src = (j < Hc) ? h1f : (j < 2 * Hc) ? hf2 : (j < 3 * Hc) ? h1b : hb2;
    x2[idx] = src[(size_t)b * Hc + (j % Hc)];
}

// ---------------- small matmul, thread-per-output: C[b,e] = dot(X[b,:K], W[e,:K]) ----------
// EPI: 0 plain, 1 softplus(acc + bias[e])
template <int EPI>
__global__ void small_mm_kernel(const float* __restrict__ X, int lda, int Kd,
                                const float* __restrict__ W,
                                float* __restrict__ C, int N, int Bn,
                                const float* __restrict__ bias) {
    int idx = blockIdx.x * blockDim.x + threadIdx.x;
    if (idx >= N * Bn) return;
    int e = idx % N;
    int b = idx / N;
    const float* xb = X + (size_t)b * lda;
    const float* wr = W + (size_t)e * Kd;
    float acc = 0.f;
    for (int k = 0; k < Kd; k++) acc += xb[k] * wr[k];
    if (EPI == 1) acc = softplusf_(acc + bias[e]);
    C[(size_t)b * N + e] = acc;
}

// ---------------- L=1 conv (only tap k=3 live) + SiLU ----------------
__global__ void conv1_silu_kernel(const float* __restrict__ xz2, const float* __restrict__ cw,
                                  const float* __restrict__ cb, float* __restrict__ u2,
                                  int total) {
    int idx = blockIdx.x * blockDim.x + threadIdx.x;
    if (idx >= total) return;
    int b = idx / DI2c;
    int c = idx % DI2c;
    float v = cb[c] + xz2[(size_t)b * (2 * DI2c) + c] * cw[c * Kc + (Kc - 1)];
    u2[idx] = siluf_(v);
}

// ---------------- L=1 scan collapse: y = (dt*u*(B.C) + D*u) * silu(z) ----------------
__global__ void scan1_kernel(const float* __restrict__ dt2, const float* __restrict__ u2,
                             const float* __restrict__ dbl2, const float* __restrict__ Dp,
                             const float* __restrict__ xz2, float* __restrict__ y2,
                             int total) {
    int idx = blockIdx.x * blockDim.x + threadIdx.x;
    if (idx >= total) return;
    int b = idx / DI2c;
    int d = idx % DI2c;
    const float* B_ = dbl2 + (size_t)b * (R2c + 2 * NSc) + R2c;
    const float* C_ = B_ + NSc;
    float bc = 0.f;
#pragma unroll
    for (int n = 0; n < NSc; n++) bc += B_[n] * C_[n];
    float uv = u2[idx];
    float y = dt2[idx] * uv * bc + Dp[d] * uv;
    float z = xz2[(size_t)b * (2 * DI2c) + DI2c + d];
    y2[idx] = y * siluf_(z);
}

// ---------------- classifier ----------------
__global__ void logits_kernel(const float* __restrict__ x, const float* __restrict__ fc_w,
                              const float* __restrict__ fc_b, float* __restrict__ out) {
    int idx = blockIdx.x * blockDim.x + threadIdx.x;
    if (idx >= Bc * 3) return;
    int b = idx / 3;
    int j = idx % 3;
    float acc = fc_b[j];
    for (int k = 0; k < D2c; k++) acc += x[(size_t)b * D2c + k] * fc_w[(size_t)j * D2c + k];
    out[idx] = acc;
}

// =====================================================================

extern "C" void kernel_launch(void* const* d_in, const int* in_sizes, int n_in,
                              void* d_out, int out_size, void* d_ws, size_t ws_size,
                              hipStream_t stream) {
    (void)in_sizes; (void)n_in; (void)out_size; (void)ws_size;

    const int*   input_ids  = (const int*)d_in[0];
    const int*   attn_mask  = (const int*)d_in[1];
    const float* embed      = (const float*)d_in[2];
    const float* bk_norm_w  = (const float*)d_in[3];
    const float* bk_in_w    = (const float*)d_in[4];
    const float* bk_conv_w  = (const float*)d_in[5];
    const float* bk_conv_b  = (const float*)d_in[6];
    const float* bk_xproj_w = (const float*)d_in[7];
    const float* bk_dtproj_w= (const float*)d_in[8];
    const float* bk_dtproj_b= (const float*)d_in[9];
    const float* bk_A_log   = (const float*)d_in[10];
    const float* bk_D       = (const float*)d_in[11];
    const float* bk_out_w   = (const float*)d_in[12];
    const float* normf_w    = (const float*)d_in[13];
    const float* l1_Wih     = (const float*)d_in[14];
    const float* l1_Whh     = (const float*)d_in[15];
    const float* l1_bih     = (const float*)d_in[16];
    const float* l1_bhh     = (const float*)d_in[17];
    const float* l2_Wih     = (const float*)d_in[18];
    const float* l2_Whh     = (const float*)d_in[19];
    const float* l2_bih     = (const float*)d_in[20];
    const float* l2_bhh     = (const float*)d_in[21];
    const float* m_in_w[2]    = {(const float*)d_in[22], (const float*)d_in[31]};
    const float* m_conv_w[2]  = {(const float*)d_in[23], (const float*)d_in[32]};
    const float* m_conv_b[2]  = {(const float*)d_in[24], (const float*)d_in[33]};
    const float* m_xproj_w[2] = {(const float*)d_in[25], (const float*)d_in[34]};
    const float* m_dtproj_w[2]= {(const float*)d_in[26], (const float*)d_in[35]};
    const float* m_dtproj_b[2]= {(const float*)d_in[27], (const float*)d_in[36]};
    const float* m_D[2]       = {(const float*)d_in[29], (const float*)d_in[38]};
    const float* m_out_w[2]   = {(const float*)d_in[30], (const float*)d_in[39]};
    const float* fc_w       = (const float*)d_in[40];
    const float* fc_b       = (const float*)d_in[41];
    float* out = (float*)d_out;

    // ---- workspace layout (floats, all offsets multiple of 4 -> 16B aligned) ----
    float* W = (float*)d_ws;
    size_t off = 0;
    float* h    = W + off; off += (size_t)Bc * Lc * Dc;        // 786432
    float* xn   = W + off; off += (size_t)Bc * Lc * Dc;
    float* xz   = W + off; off += (size_t)Bc * Lc * 2 * DIc;   // 3145728
    float* u    = W + off; off += (size_t)Bc * Lc * DIc;
    float* dbl  = W + off; off += (size_t)Bc * Lc * 80;
    float* dt   = W + off; off += (size_t)Bc * Lc * DIc;
    float* yb   = W + off; off += (size_t)Bc * Lc * DIc;
    float* pooled = W + off; off += (size_t)Bc * Dc;
    float* h1f  = W + off; off += 400;
    float* h1b  = W + off; off += 400;
    float* hf1  = W + off; off += 400;
    float* cf1  = W + off; off += 400;
    float* hf2  = W + off; off += 400;
    float* cf2  = W + off; off += 400;
    float* hb1  = W + off; off += 400;
    float* cb1  = W + off; off += 400;
    float* hb2  = W + off; off += 400;
    float* cb2  = W + off; off += 400;
    float* cjunk= W + off; off += 400;
    float* x2   = W + off; off += (size_t)Bc * 4 * Hc;         // (2,800)
    float* xz2  = W + off; off += (size_t)Bc * 2 * DI2c;       // (2,3200)
    float* u2   = W + off; off += (size_t)Bc * DI2c;
    float* dbl2 = W + off; off += (size_t)Bc * (R2c + 2 * NSc);// (2,82)
    float* dt2  = W + off; off += (size_t)Bc * DI2c;
    float* y2   = W + off; off += (size_t)Bc * DI2c;
    float* xm1  = W + off; off += (size_t)Bc * D2c;
    float* xm2  = W + off; off += (size_t)Bc * D2c;

    const int BL = Bc * Lc;  // 1024

    // ---- embedding ----
    embed_kernel<<<(BL * Dc) / 256, 256, 0, stream>>>(input_ids, embed, h, BL * Dc, Dc);

    // ---- 24 mamba layers ----
    for (int layer = 0; layer < NLc; layer++) {
        const float* norm_w   = bk_norm_w + (size_t)layer * Dc;
        const float* in_w     = bk_in_w + (size_t)layer * 2 * DIc * Dc;
        const float* conv_w   = bk_conv_w + (size_t)layer * DIc * Kc;
        const float* conv_b   = bk_conv_b + (size_t)layer * DIc;
        const float* xproj_w  = bk_xproj_w + (size_t)layer * 80 * DIc;
        const float* dtproj_w = bk_dtproj_w + (size_t)layer * DIc * Rc;
        const float* dtproj_b = bk_dtproj_b + (size_t)layer * DIc;
        const float* A_log    = bk_A_log + (size_t)layer * DIc * NSc;
        const float* Dp       = bk_D + (size_t)layer * DIc;
        const float* out_w    = bk_out_w + (size_t)layer * Dc * DIc;

        rmsnorm_kernel<<<BL, 256, 0, stream>>>(h, norm_w, xn, Dc);

        gemm_nt<0><<<dim3((2 * DIc) / 64, BL / 64), 256, 0, stream>>>(
            xn, Dc, in_w, Dc, xz, 2 * DIc, BL, 2 * DIc, Dc, nullptr);

        conv_silu_kernel<<<(BL * DIc) / 256, 256, 0, stream>>>(xz, conv_w, conv_b, u, BL * DIc);

        gemm_nt<0><<<dim3(2, BL / 64), 256, 0, stream>>>(
            u, DIc, xproj_w, DIc, dbl, 80, BL, 80, DIc, nullptr);

        gemm_nt<1><<<dim3(DIc / 64, BL / 64), 256, 0, stream>>>(
            dbl, 80, dtproj_w, Rc, dt, DIc, BL, DIc, Rc, dtproj_b);

        scan_kernel<<<(Bc * DIc * NSc) / 256, 256, 0, stream>>>(dt, u, dbl, A_log, Dp, yb);

        zmul_kernel<<<(BL * DIc) / 256, 256, 0, stream>>>(yb, xz, BL * DIc);

        gemm_nt<2><<<dim3(Dc / 64, BL / 64), 256, 0, stream>>>(
            yb, DIc, out_w, DIc, h, Dc, BL, Dc, DIc, nullptr);
    }

    // ---- final norm + pooling ----
    rmsnorm_kernel<<<BL, 256, 0, stream>>>(h, normf_w, xn, Dc);
    pool_kernel<<<(Bc * Dc + 255) / 256, 256, 0, stream>>>(xn, attn_mask, pooled, Bc * Dc);

    // ---- LSTMs ----
    const size_t w1s = (size_t)4 * Hc * Dc;   // l1 Wih dir stride
    const size_t whs = (size_t)4 * Hc * Hc;   // Whh / l2 Wih dir stride
    lstm_cell_kernel<<<Bc, 256, 0, stream>>>(pooled, Dc, nullptr, nullptr,
        l1_Wih, l1_Whh, l1_bih, l1_bhh, h1f, cjunk);
    lstm_cell_kernel<<<Bc, 256, 0, stream>>>(pooled, Dc, nullptr, nullptr,
        l1_Wih + w1s, l1_Whh + whs, l1_bih + 4 * Hc, l1_bhh + 4 * Hc, h1b, cjunk);
    lstm_cell_kernel<<<Bc, 256, 0, stream>>>(h1f, Hc, nullptr, nullptr,
        l2_Wih, l2_Whh, l2_bih, l2_bhh, hf1, cf1);
    lstm_cell_kernel<<<Bc, 256, 0, stream>>>(h1b, Hc, hf1, cf1,
        l2_Wih, l2_Whh, l2_bih, l2_bhh, hf2, cf2);
    lstm_cell_kernel<<<Bc, 256, 0, stream>>>(h1b, Hc, nullptr, nullptr,
        l2_Wih + whs, l2_Whh + whs, l2_bih + 4 * Hc, l2_bhh + 4 * Hc, hb1, cb1);
    lstm_cell_kernel<<<Bc, 256, 0, stream>>>(h1f, Hc, hb1, cb1,
        l2_Wih + whs, l2_Whh + whs, l2_bih + 4 * Hc, l2_bhh + 4 * Hc, hb2, cb2);

    concat_kernel<<<(Bc * 4 * Hc + 255) / 256, 256, 0, stream>>>(h1f, hf2, h1b, hb2, x2,
                                                                 Bc * 4 * Hc);

    // ---- two small mamba mixers (L=1) ----
    const float* mx = x2;
    float* mouts[2] = {xm1, xm2};
    for (int m = 0; m < 2; m++) {
        small_mm_kernel<0><<<(Bc * 2 * DI2c + 255) / 256, 256, 0, stream>>>(
            mx, D2c, D2c, m_in_w[m], xz2, 2 * DI2c, Bc, nullptr);
        conv1_silu_kernel<<<(Bc * DI2c + 255) / 256, 256, 0, stream>>>(
            xz2, m_conv_w[m], m_conv_b[m], u2, Bc * DI2c);
        small_mm_kernel<0><<<(Bc * (R2c + 2 * NSc) + 255) / 256, 256, 0, stream>>>(
            u2, DI2c, DI2c, m_xproj_w[m], dbl2, R2c + 2 * NSc, Bc, nullptr);
        small_mm_kernel<1><<<(Bc * DI2c + 255) / 256, 256, 0, stream>>>(
            dbl2, R2c + 2 * NSc, R2c, m_dtproj_w[m], dt2, DI2c, Bc, m_dtproj_b[m]);
        scan1_kernel<<<(Bc * DI2c + 255) / 256, 256, 0, stream>>>(
            dt2, u2, dbl2, m_D[m], xz2, y2, Bc * DI2c);
        small_mm_kernel<0><<<(Bc * D2c + 255) / 256, 256, 0, stream>>>(
            y2, DI2c, DI2c, m_out_w[m], mouts[m], D2c, Bc, nullptr);
        mx = mouts[m];
    }

    // ---- classifier ----
    logits_kernel<<<1, 64, 0, stream>>>(xm2, fc_w, fc_b, out);
}

// Round 2
// 11014.836 us; speedup vs baseline: 1.5338x; 1.5338x over previous
//
#include <hip/hip_runtime.h>
#include <cstddef>
#include <cmath>

// ---------------- constants ----------------
#define Bc   2
#define Lc   512
#define Dc   768
#define NLc  24
#define NSc  16
#define Kc   4
#define DIc  1536
#define Rc   48
#define Hc   200
#define D2c  800
#define DI2c 1600
#define R2c  50

#define S0w (2 * DIc * Dc)     // in_w   2359296
#define S1w (Dc * DIc)         // out_w  1179648
#define S2w (80 * DIc)         // xproj  122880
#define S3w (DIc * Rc)         // dtproj 73728
#define WTOT (S0w + S1w + S2w + S3w)  // 3735552

typedef __attribute__((ext_vector_type(8))) short bf16x8_t;
typedef __attribute__((ext_vector_type(4))) float f32x4_t;
typedef __attribute__((ext_vector_type(4))) short s16x4_t;

__device__ __forceinline__ float sigmoidf_(float x) { return 1.f / (1.f + expf(-x)); }
__device__ __forceinline__ float siluf_(float x)    { return x / (1.f + expf(-x)); }
__device__ __forceinline__ float softplusf_(float x) {
    return x > 0.f ? x + log1pf(expf(-x)) : log1pf(expf(x));
}

// Truncation split: x = hi + lo + O(2^-16 x). hi = trunc-to-bf16(x) (exact
// subtraction: d = x - hi is exact in fp32), lo = trunc-to-bf16(d).
__device__ __forceinline__ void split2(float x, unsigned short& h, unsigned short& l) {
    unsigned u = __float_as_uint(x);
    h = (unsigned short)(u >> 16);
    float hf = __uint_as_float(u & 0xFFFF0000u);
    float d = x - hf;
    l = (unsigned short)(__float_as_uint(d) >> 16);
}

// ---------------- embedding lookup ----------------
__global__ void embed_kernel(const int* __restrict__ ids, const float* __restrict__ emb,
                             float* __restrict__ h, int total, int Dd) {
    int idx = blockIdx.x * blockDim.x + threadIdx.x;
    if (idx >= total) return;
    int d = idx % Dd;
    int t = idx / Dd;
    h[idx] = emb[(size_t)ids[t] * Dd + d];
}

// ---------------- per-layer weight split fp32 -> bf16 hi/lo ----------------
__global__ __launch_bounds__(256) void wconv_kernel(const float* __restrict__ w_in,
                                                    const float* __restrict__ w_out,
                                                    const float* __restrict__ w_xp,
                                                    const float* __restrict__ w_dt,
                                                    unsigned short* __restrict__ whi,
                                                    unsigned short* __restrict__ wlo) {
    int e = (blockIdx.x * 256 + threadIdx.x) * 4;
    if (e >= WTOT) return;
    const float* src;
    if (e < S0w)                  src = w_in  + e;
    else if (e < S0w + S1w)       src = w_out + (e - S0w);
    else if (e < S0w + S1w + S2w) src = w_xp  + (e - S0w - S1w);
    else                          src = w_dt  + (e - S0w - S1w - S2w);
    float4 v = *(const float4*)src;
    unsigned short h0, l0, h1, l1, h2, l2, h3, l3;
    split2(v.x, h0, l0); split2(v.y, h1, l1); split2(v.z, h2, l2); split2(v.w, h3, l3);
    s16x4_t hv = {(short)h0, (short)h1, (short)h2, (short)h3};
    s16x4_t lv = {(short)l0, (short)l1, (short)l2, (short)l3};
    *(s16x4_t*)(whi + e) = hv;
    *(s16x4_t*)(wlo + e) = lv;
}

// ---------------- rmsnorm (one block per row), emits fp32 + split ----------------
__global__ __launch_bounds__(256) void rmsnorm_kernel(const float* __restrict__ x,
                                                      const float* __restrict__ w,
                                                      float* __restrict__ out,
                                                      unsigned short* __restrict__ ohi,
                                                      unsigned short* __restrict__ olo,
                                                      int Dd) {
    int row = blockIdx.x;
    const float* xr = x + (size_t)row * Dd;
    float ss = 0.f;
    for (int d = threadIdx.x; d < Dd; d += 256) { float v = xr[d]; ss += v * v; }
    for (int off = 32; off > 0; off >>= 1) ss += __shfl_down(ss, off);
    __shared__ float sw[4];
    __shared__ float sinv;
    if ((threadIdx.x & 63) == 0) sw[threadIdx.x >> 6] = ss;
    __syncthreads();
    if (threadIdx.x == 0) sinv = rsqrtf((sw[0] + sw[1] + sw[2] + sw[3]) / (float)Dd + 1e-5f);
    __syncthreads();
    float inv = sinv;
    for (int d = threadIdx.x; d < Dd; d += 256) {
        float v = xr[d] * inv * w[d];
        out[(size_t)row * Dd + d] = v;
        unsigned short hh, ll;
        split2(v, hh, ll);
        ohi[(size_t)row * Dd + d] = hh;
        olo[(size_t)row * Dd + d] = ll;
    }
}

// ---------------- split-bf16 MFMA GEMM:  C[m,n] = sum_k A[m,k]*B[n,k] ----------------
// A,B given pre-split (hi,lo bf16 as raw ushort). 3 MFMAs per tile: hh + lh + hl.
// EPI: 0 plain, 1 softplus(acc+bias[n]), 2 residual add. SPLITOUT: also store split C.
template <int BM, int BN, int EPI, bool SPLITOUT>
__global__ __launch_bounds__(256) void gemm_split(
    const unsigned short* __restrict__ Ah, const unsigned short* __restrict__ Al, int lda,
    const unsigned short* __restrict__ Bh, const unsigned short* __restrict__ Bl, int ldb,
    float* __restrict__ C, int ldc,
    unsigned short* __restrict__ Chi, unsigned short* __restrict__ Clo,
    int M, int N, int Kd, const float* __restrict__ bias) {
    constexpr int SK = 40;          // 32 + 8 pad (80 B rows -> 2-way banks = free)
    constexpr int TM = BM / 32;
    constexpr int TN = BN / 32;
    __shared__ short smem[(BM + BN) * 2 * SK];
    short* As_h = smem;
    short* As_l = smem + BM * SK;
    short* Bs_h = smem + 2 * BM * SK;
    short* Bs_l = smem + 2 * BM * SK + BN * SK;

    int tid = threadIdx.x;
    int lane = tid & 63;
    int wave = tid >> 6;
    int ln = lane & 15;
    int q  = lane >> 4;
    int bm = blockIdx.y * BM;
    int bn = blockIdx.x * BN;
    int wm = (wave & 1) * (BM / 2);
    int wn = (wave >> 1) * (BN / 2);

    f32x4_t acc[TM][TN];
#pragma unroll
    for (int i = 0; i < TM; i++)
#pragma unroll
        for (int j = 0; j < TN; j++) acc[i][j] = f32x4_t{0.f, 0.f, 0.f, 0.f};

    for (int k0 = 0; k0 < Kd; k0 += 32) {
        // stage A (BM x 32 hi + lo)
        for (int idx = tid * 8; idx < BM * 32; idx += 2048) {
            int r = idx >> 5, c = idx & 31;
            int gr = bm + r;
            bf16x8_t vh = {0, 0, 0, 0, 0, 0, 0, 0};
            bf16x8_t vl = {0, 0, 0, 0, 0, 0, 0, 0};
            if (gr < M && (k0 + c) < Kd) {
                size_t o = (size_t)gr * lda + k0 + c;
                vh = *(const bf16x8_t*)(Ah + o);
                vl = *(const bf16x8_t*)(Al + o);
            }
            *(bf16x8_t*)(As_h + r * SK + c) = vh;
            *(bf16x8_t*)(As_l + r * SK + c) = vl;
        }
        // stage B (BN x 32 hi + lo)
        for (int idx = tid * 8; idx < BN * 32; idx += 2048) {
            int r = idx >> 5, c = idx & 31;
            int gr = bn + r;
            bf16x8_t vh = {0, 0, 0, 0, 0, 0, 0, 0};
            bf16x8_t vl = {0, 0, 0, 0, 0, 0, 0, 0};
            if (gr < N && (k0 + c) < Kd) {
                size_t o = (size_t)gr * ldb + k0 + c;
                vh = *(const bf16x8_t*)(Bh + o);
                vl = *(const bf16x8_t*)(Bl + o);
            }
            *(bf16x8_t*)(Bs_h + r * SK + c) = vh;
            *(bf16x8_t*)(Bs_l + r * SK + c) = vl;
        }
        __syncthreads();

        bf16x8_t ah[TM], al[TM], bh[TN], bl[TN];
#pragma unroll
        for (int i = 0; i < TM; i++) {
            int row = wm + i * 16 + ln;
            ah[i] = *(const bf16x8_t*)(As_h + row * SK + q * 8);
            al[i] = *(const bf16x8_t*)(As_l + row * SK + q * 8);
        }
#pragma unroll
        for (int j = 0; j < TN; j++) {
            int row = wn + j * 16 + ln;
            bh[j] = *(const bf16x8_t*)(Bs_h + row * SK + q * 8);
            bl[j] = *(const bf16x8_t*)(Bs_l + row * SK + q * 8);
        }
#pragma unroll
        for (int i = 0; i < TM; i++)
#pragma unroll
            for (int j = 0; j < TN; j++)
                acc[i][j] = __builtin_amdgcn_mfma_f32_16x16x32_bf16(ah[i], bh[j], acc[i][j], 0, 0, 0);
#pragma unroll
        for (int i = 0; i < TM; i++)
#pragma unroll
            for (int j = 0; j < TN; j++)
                acc[i][j] = __builtin_amdgcn_mfma_f32_16x16x32_bf16(al[i], bh[j], acc[i][j], 0, 0, 0);
#pragma unroll
        for (int i = 0; i < TM; i++)
#pragma unroll
            for (int j = 0; j < TN; j++)
                acc[i][j] = __builtin_amdgcn_mfma_f32_16x16x32_bf16(ah[i], bl[j], acc[i][j], 0, 0, 0);
        __syncthreads();
    }

    // epilogue: C/D layout col=lane&15, row=quad*4+reg
#pragma unroll
    for (int i = 0; i < TM; i++) {
#pragma unroll
        for (int j = 0; j < TN; j++) {
#pragma unroll
            for (int r = 0; r < 4; r++) {
                int row = bm + wm + i * 16 + q * 4 + r;
                int col = bn + wn + j * 16 + ln;
                if (row < M && col < N) {
                    float v = acc[i][j][r];
                    if (EPI == 1) v = softplusf_(v + bias[col]);
                    if (EPI == 2) v += C[(size_t)row * ldc + col];
                    C[(size_t)row * ldc + col] = v;
                    if (SPLITOUT) {
                        unsigned short hh, ll;
                        split2(v, hh, ll);
                        Chi[(size_t)row * ldc + col] = hh;
                        Clo[(size_t)row * ldc + col] = ll;
                    }
                }
            }
        }
    }
}

// ---------------- causal conv (K=4) + SiLU, emits fp32 + split ----------------
__global__ void conv_silu_kernel(const float* __restrict__ xz, const float* __restrict__ cw,
                                 const float* __restrict__ cb, float* __restrict__ u,
                                 unsigned short* __restrict__ uhi, unsigned short* __restrict__ ulo,
                                 int total) {
    int idx = blockIdx.x * blockDim.x + threadIdx.x;
    if (idx >= total) return;
    int c = idx % DIc;
    int l = (idx / DIc) % Lc;
    int b = idx / (DIc * Lc);
    float acc = cb[c];
#pragma unroll
    for (int k = 0; k < Kc; k++) {
        int ls = l - (Kc - 1) + k;
        if (ls >= 0) acc += xz[((size_t)(b * Lc + ls)) * (2 * DIc) + c] * cw[c * Kc + k];
    }
    float v = siluf_(acc);
    u[idx] = v;
    unsigned short hh, ll;
    split2(v, hh, ll);
    uhi[idx] = hh;
    ulo[idx] = ll;
}

// ---------------- selective scan: thread per (b,d,n) ----------------
__global__ __launch_bounds__(256) void scan_kernel(const float* __restrict__ dt,
                                                   const float* __restrict__ u,
                                                   const float* __restrict__ dbl,
                                                   const float* __restrict__ A_log,
                                                   const float* __restrict__ Dp,
                                                   float* __restrict__ y) {
    int gid = blockIdx.x * blockDim.x + threadIdx.x;
    int n = gid & 15;
    int d = (gid >> 4) % DIc;
    int b = gid / (16 * DIc);
    float A  = -expf(A_log[d * NSc + n]);
    float Dv = Dp[d];
    float h = 0.f;
    const float* dtp = dt + (size_t)b * Lc * DIc + d;
    const float* up  = u + (size_t)b * Lc * DIc + d;
    const float* blp = dbl + (size_t)b * Lc * 80 + Rc + n;  // B at +0, C at +16
    float* yp = y + (size_t)b * Lc * DIc + d;

    float dtv = dtp[0], uv = up[0], Bv = blp[0], Cv = blp[16];
    for (int l = 0; l < Lc; l++) {
        float dtn = 0.f, un = 0.f, Bn2 = 0.f, Cn = 0.f;
        if (l + 1 < Lc) {
            size_t o = (size_t)(l + 1) * DIc;
            dtn = dtp[o]; un = up[o];
            size_t ob = (size_t)(l + 1) * 80;
            Bn2 = blp[ob]; Cn = blp[ob + 16];
        }
        float dA = expf(dtv * A);
        h = dA * h + dtv * Bv * uv;
        float p = h * Cv;
        p += __shfl_xor(p, 1);
        p += __shfl_xor(p, 2);
        p += __shfl_xor(p, 4);
        p += __shfl_xor(p, 8);
        if (n == 0) yp[(size_t)l * DIc] = p + Dv * uv;
        dtv = dtn; uv = un; Bv = Bn2; Cv = Cn;
    }
}

// ---------------- yb_split = (y * silu(z)) split ----------------
__global__ void zmul_kernel(const float* __restrict__ y, const float* __restrict__ xz,
                            unsigned short* __restrict__ yhi, unsigned short* __restrict__ ylo,
                            int total) {
    int idx = blockIdx.x * blockDim.x + threadIdx.x;
    if (idx >= total) return;
    int c = idx % DIc;
    int bl = idx / DIc;
    float z = xz[(size_t)bl * (2 * DIc) + DIc + c];
    float v = y[idx] * siluf_(z);
    unsigned short hh, ll;
    split2(v, hh, ll);
    yhi[idx] = hh;
    ylo[idx] = ll;
}

// ---------------- masked mean pool ----------------
__global__ void pool_kernel(const float* __restrict__ xn, const int* __restrict__ mask,
                            float* __restrict__ pooled, int total) {
    int idx = blockIdx.x * blockDim.x + threadIdx.x;
    if (idx >= total) return;
    int b = idx / Dc;
    int d = idx % Dc;
    float s = 0.f, ms = 0.f;
    for (int l = 0; l < Lc; l++) {
        float m = (float)mask[b * Lc + l];
        s += xn[((size_t)(b * Lc + l)) * Dc + d] * m;
        ms += m;
    }
    pooled[idx] = s / ms;
}

// ---------------- LSTM cell (one block per batch element) ----------------
__global__ __launch_bounds__(256) void lstm_cell_kernel(const float* __restrict__ x, int xdim,
                                                        const float* __restrict__ h0,
                                                        const float* __restrict__ c0,
                                                        const float* __restrict__ Wih,
                                                        const float* __restrict__ Whh,
                                                        const float* __restrict__ bih,
                                                        const float* __restrict__ bhh,
                                                        float* __restrict__ h_out,
                                                        float* __restrict__ c_out) {
    __shared__ float g[4 * Hc];
    int b = blockIdx.x;
    int tid = threadIdx.x;
    const float* xb = x + (size_t)b * xdim;
    for (int j = tid; j < 4 * Hc; j += 256) {
        float acc = bih[j] + bhh[j];
        const float* wr = Wih + (size_t)j * xdim;
        for (int k = 0; k < xdim; k++) acc += xb[k] * wr[k];
        if (h0) {
            const float* hr = Whh + (size_t)j * Hc;
            const float* hb = h0 + (size_t)b * Hc;
            for (int k = 0; k < Hc; k++) acc += hb[k] * hr[k];
        }
        g[j] = acc;
    }
    __syncthreads();
    for (int j = tid; j < Hc; j += 256) {
        float ig = sigmoidf_(g[j]);
        float fg = sigmoidf_(g[Hc + j]);
        float gg = tanhf(g[2 * Hc + j]);
        float og = sigmoidf_(g[3 * Hc + j]);
        float cprev = c0 ? c0[(size_t)b * Hc + j] : 0.f;
        float c = fg * cprev + ig * gg;
        h_out[(size_t)b * Hc + j] = og * tanhf(c);
        if (c_out) c_out[(size_t)b * Hc + j] = c;
    }
}

// ---------------- concat [h1f | hf2 | h1b | hb2] -> (B, 800) ----------------
__global__ void concat_kernel(const float* __restrict__ h1f, const float* __restrict__ hf2,
                              const float* __restrict__ h1b, const float* __restrict__ hb2,
                              float* __restrict__ x2, int total) {
    int idx = blockIdx.x * blockDim.x + threadIdx.x;
    if (idx >= total) return;
    int b = idx / (4 * Hc);
    int j = idx % (4 * Hc);
    const float* src = (j < Hc) ? h1f : (j < 2 * Hc) ? hf2 : (j < 3 * Hc) ? h1b : hb2;
    x2[idx] = src[(size_t)b * Hc + (j % Hc)];
}

// ---------------- small matmul, thread-per-output ----------------
template <int EPI>
__global__ void small_mm_kernel(const float* __restrict__ X, int lda, int Kd,
                                const float* __restrict__ W,
                                float* __restrict__ C, int N, int Bn,
                                const float* __restrict__ bias) {
    int idx = blockIdx.x * blockDim.x + threadIdx.x;
    if (idx >= N * Bn) return;
    int e = idx % N;
    int b = idx / N;
    const float* xb = X + (size_t)b * lda;
    const float* wr = W + (size_t)e * Kd;
    float acc = 0.f;
    for (int k = 0; k < Kd; k++) acc += xb[k] * wr[k];
    if (EPI == 1) acc = softplusf_(acc + bias[e]);
    C[(size_t)b * N + e] = acc;
}

// ---------------- L=1 conv (only tap k=3 live) + SiLU ----------------
__global__ void conv1_silu_kernel(const float* __restrict__ xz2, const float* __restrict__ cw,
                                  const float* __restrict__ cb, float* __restrict__ u2,
                                  int total) {
    int idx = blockIdx.x * blockDim.x + threadIdx.x;
    if (idx >= total) return;
    int b = idx / DI2c;
    int c = idx % DI2c;
    float v = cb[c] + xz2[(size_t)b * (2 * DI2c) + c] * cw[c * Kc + (Kc - 1)];
    u2[idx] = siluf_(v);
}

// ---------------- L=1 scan collapse ----------------
__global__ void scan1_kernel(const float* __restrict__ dt2, const float* __restrict__ u2,
                             const float* __restrict__ dbl2, const float* __restrict__ Dp,
                             const float* __restrict__ xz2, float* __restrict__ y2,
                             int total) {
    int idx = blockIdx.x * blockDim.x + threadIdx.x;
    if (idx >= total) return;
    int b = idx / DI2c;
    int d = idx % DI2c;
    const float* B_ = dbl2 + (size_t)b * (R2c + 2 * NSc) + R2c;
    const float* C_ = B_ + NSc;
    float bc = 0.f;
#pragma unroll
    for (int n = 0; n < NSc; n++) bc += B_[n] * C_[n];
    float uv = u2[idx];
    float y = dt2[idx] * uv * bc + Dp[d] * uv;
    float z = xz2[(size_t)b * (2 * DI2c) + DI2c + d];
    y2[idx] = y * siluf_(z);
}

// ---------------- classifier ----------------
__global__ void logits_kernel(const float* __restrict__ x, const float* __restrict__ fc_w,
                              const float* __restrict__ fc_b, float* __restrict__ out) {
    int idx = blockIdx.x * blockDim.x + threadIdx.x;
    if (idx >= Bc * 3) return;
    int b = idx / 3;
    int j = idx % 3;
    float acc = fc_b[j];
    for (int k = 0; k < D2c; k++) acc += x[(size_t)b * D2c + k] * fc_w[(size_t)j * D2c + k];
    out[idx] = acc;
}

// =====================================================================

extern "C" void kernel_launch(void* const* d_in, const int* in_sizes, int n_in,
                              void* d_out, int out_size, void* d_ws, size_t ws_size,
                              hipStream_t stream) {
    (void)in_sizes; (void)n_in; (void)out_size; (void)ws_size;

    const int*   input_ids  = (const int*)d_in[0];
    const int*   attn_mask  = (const int*)d_in[1];
    const float* embed      = (const float*)d_in[2];
    const float* bk_norm_w  = (const float*)d_in[3];
    const float* bk_in_w    = (const float*)d_in[4];
    const float* bk_conv_w  = (const float*)d_in[5];
    const float* bk_conv_b  = (const float*)d_in[6];
    const float* bk_xproj_w = (const float*)d_in[7];
    const float* bk_dtproj_w= (const float*)d_in[8];
    const float* bk_dtproj_b= (const float*)d_in[9];
    const float* bk_A_log   = (const float*)d_in[10];
    const float* bk_D       = (const float*)d_in[11];
    const float* bk_out_w   = (const float*)d_in[12];
    const float* normf_w    = (const float*)d_in[13];
    const float* l1_Wih     = (const float*)d_in[14];
    const float* l1_Whh     = (const float*)d_in[15];
    const float* l1_bih     = (const float*)d_in[16];
    const float* l1_bhh     = (const float*)d_in[17];
    const float* l2_Wih     = (const float*)d_in[18];
    const float* l2_Whh     = (const float*)d_in[19];
    const float* l2_bih     = (const float*)d_in[20];
    const float* l2_bhh     = (const float*)d_in[21];
    const float* m_in_w[2]    = {(const float*)d_in[22], (const float*)d_in[31]};
    const float* m_conv_w[2]  = {(const float*)d_in[23], (const float*)d_in[32]};
    const float* m_conv_b[2]  = {(const float*)d_in[24], (const float*)d_in[33]};
    const float* m_xproj_w[2] = {(const float*)d_in[25], (const float*)d_in[34]};
    const float* m_dtproj_w[2]= {(const float*)d_in[26], (const float*)d_in[35]};
    const float* m_dtproj_b[2]= {(const float*)d_in[27], (const float*)d_in[36]};
    const float* m_D[2]       = {(const float*)d_in[29], (const float*)d_in[38]};
    const float* m_out_w[2]   = {(const float*)d_in[30], (const float*)d_in[39]};
    const float* fc_w       = (const float*)d_in[40];
    const float* fc_b       = (const float*)d_in[41];
    float* out = (float*)d_out;

    // ---- workspace layout: fp32 region, then ushort region ----
    float* W = (float*)d_ws;
    size_t off = 0;
    float* h    = W + off; off += (size_t)Bc * Lc * Dc;        // 786432
    float* xn   = W + off; off += (size_t)Bc * Lc * Dc;
    float* xz   = W + off; off += (size_t)Bc * Lc * 2 * DIc;   // 3145728
    float* u    = W + off; off += (size_t)Bc * Lc * DIc;
    float* dbl  = W + off; off += (size_t)Bc * Lc * 80;
    float* dt   = W + off; off += (size_t)Bc * Lc * DIc;
    float* yb   = W + off; off += (size_t)Bc * Lc * DIc;
    float* pooled = W + off; off += (size_t)Bc * Dc;
    float* h1f  = W + off; off += 400;
    float* h1b  = W + off; off += 400;
    float* hf1  = W + off; off += 400;
    float* cf1  = W + off; off += 400;
    float* hf2  = W + off; off += 400;
    float* cf2  = W + off; off += 400;
    float* hb1  = W + off; off += 400;
    float* cb1  = W + off; off += 400;
    float* hb2  = W + off; off += 400;
    float* cb2  = W + off; off += 400;
    float* cjunk= W + off; off += 400;
    float* x2   = W + off; off += (size_t)Bc * 4 * Hc;
    float* xz2  = W + off; off += (size_t)Bc * 2 * DI2c;
    float* u2   = W + off; off += (size_t)Bc * DI2c;
    float* dbl2 = W + off; off += (size_t)Bc * (R2c + 2 * NSc);
    float* dt2  = W + off; off += (size_t)Bc * DI2c;
    float* y2   = W + off; off += (size_t)Bc * DI2c;
    float* xm1  = W + off; off += (size_t)Bc * D2c;
    float* xm2  = W + off; off += (size_t)Bc * D2c;

    unsigned short* U = (unsigned short*)(W + off);
    size_t uo = 0;
    unsigned short* whi   = U + uo; uo += (size_t)WTOT;
    unsigned short* wlo   = U + uo; uo += (size_t)WTOT;
    unsigned short* xn_hi = U + uo; uo += (size_t)Bc * Lc * Dc;
    unsigned short* xn_lo = U + uo; uo += (size_t)Bc * Lc * Dc;
    unsigned short* u_hi  = U + uo; uo += (size_t)Bc * Lc * DIc;
    unsigned short* u_lo  = U + uo; uo += (size_t)Bc * Lc * DIc;
    unsigned short* yb_hi = U + uo; uo += (size_t)Bc * Lc * DIc;
    unsigned short* yb_lo = U + uo; uo += (size_t)Bc * Lc * DIc;
    unsigned short* db_hi = U + uo; uo += (size_t)Bc * Lc * 80;
    unsigned short* db_lo = U + uo; uo += (size_t)Bc * Lc * 80;

    const int BL = Bc * Lc;  // 1024

    // ---- embedding ----
    embed_kernel<<<(BL * Dc) / 256, 256, 0, stream>>>(input_ids, embed, h, BL * Dc, Dc);

    // ---- 24 mamba layers ----
    for (int layer = 0; layer < NLc; layer++) {
        const float* norm_w   = bk_norm_w + (size_t)layer * Dc;
        const float* in_w     = bk_in_w + (size_t)layer * 2 * DIc * Dc;
        const float* conv_w   = bk_conv_w + (size_t)layer * DIc * Kc;
        const float* conv_b   = bk_conv_b + (size_t)layer * DIc;
        const float* xproj_w  = bk_xproj_w + (size_t)layer * 80 * DIc;
        const float* dtproj_w = bk_dtproj_w + (size_t)layer * DIc * Rc;
        const float* dtproj_b = bk_dtproj_b + (size_t)layer * DIc;
        const float* A_log    = bk_A_log + (size_t)layer * DIc * NSc;
        const float* Dp       = bk_D + (size_t)layer * DIc;
        const float* out_w    = bk_out_w + (size_t)layer * Dc * DIc;

        wconv_kernel<<<WTOT / 1024, 256, 0, stream>>>(in_w, out_w, xproj_w, dtproj_w, whi, wlo);

        rmsnorm_kernel<<<BL, 256, 0, stream>>>(h, norm_w, xn, xn_hi, xn_lo, Dc);

        // in_proj: (1024 x 768) x (3072 x 768)^T
        gemm_split<128, 128, 0, false><<<dim3((2 * DIc) / 128, BL / 128), 256, 0, stream>>>(
            xn_hi, xn_lo, Dc, whi, wlo, Dc, xz, 2 * DIc, nullptr, nullptr,
            BL, 2 * DIc, Dc, nullptr);

        conv_silu_kernel<<<(BL * DIc) / 256, 256, 0, stream>>>(xz, conv_w, conv_b,
                                                               u, u_hi, u_lo, BL * DIc);

        // xproj: (1024 x 1536) x (80 x 1536)^T, split-out for dtproj
        gemm_split<64, 64, 0, true><<<dim3(2, BL / 64), 256, 0, stream>>>(
            u_hi, u_lo, DIc, whi + S0w + S1w, wlo + S0w + S1w, DIc, dbl, 80, db_hi, db_lo,
            BL, 80, DIc, nullptr);

        // dtproj: (1024 x 48[of 80]) x (1536 x 48)^T, softplus+bias
        gemm_split<64, 64, 1, false><<<dim3(DIc / 64, BL / 64), 256, 0, stream>>>(
            db_hi, db_lo, 80, whi + S0w + S1w + S2w, wlo + S0w + S1w + S2w, Rc,
            dt, DIc, nullptr, nullptr, BL, DIc, Rc, dtproj_b);

        scan_kernel<<<(Bc * DIc * NSc) / 256, 256, 0, stream>>>(dt, u, dbl, A_log, Dp, yb);

        zmul_kernel<<<(BL * DIc) / 256, 256, 0, stream>>>(yb, xz, yb_hi, yb_lo, BL * DIc);

        // out_proj: (1024 x 1536) x (768 x 1536)^T, residual add into h
        gemm_split<64, 64, 2, false><<<dim3(Dc / 64, BL / 64), 256, 0, stream>>>(
            yb_hi, yb_lo, DIc, whi + S0w, wlo + S0w, DIc, h, Dc, nullptr, nullptr,
            BL, Dc, DIc, nullptr);
    }

    // ---- final norm + pooling ----
    rmsnorm_kernel<<<BL, 256, 0, stream>>>(h, normf_w, xn, xn_hi, xn_lo, Dc);
    pool_kernel<<<(Bc * Dc + 255) / 256, 256, 0, stream>>>(xn, attn_mask, pooled, Bc * Dc);

    // ---- LSTMs ----
    const size_t w1s = (size_t)4 * Hc * Dc;
    const size_t whs = (size_t)4 * Hc * Hc;
    lstm_cell_kernel<<<Bc, 256, 0, stream>>>(pooled, Dc, nullptr, nullptr,
        l1_Wih, l1_Whh, l1_bih, l1_bhh, h1f, cjunk);
    lstm_cell_kernel<<<Bc, 256, 0, stream>>>(pooled, Dc, nullptr, nullptr,
        l1_Wih + w1s, l1_Whh + whs, l1_bih + 4 * Hc, l1_bhh + 4 * Hc, h1b, cjunk);
    lstm_cell_kernel<<<Bc, 256, 0, stream>>>(h1f, Hc, nullptr, nullptr,
        l2_Wih, l2_Whh, l2_bih, l2_bhh, hf1, cf1);
    lstm_cell_kernel<<<Bc, 256, 0, stream>>>(h1b, Hc, hf1, cf1,
        l2_Wih, l2_Whh, l2_bih, l2_bhh, hf2, cf2);
    lstm_cell_kernel<<<Bc, 256, 0, stream>>>(h1b, Hc, nullptr, nullptr,
        l2_Wih + whs, l2_Whh + whs, l2_bih + 4 * Hc, l2_bhh + 4 * Hc, hb1, cb1);
    lstm_cell_kernel<<<Bc, 256, 0, stream>>>(h1f, Hc, hb1, cb1,
        l2_Wih + whs, l2_Whh + whs, l2_bih + 4 * Hc, l2_bhh + 4 * Hc, hb2, cb2);

    concat_kernel<<<(Bc * 4 * Hc + 255) / 256, 256, 0, stream>>>(h1f, hf2, h1b, hb2, x2,
                                                                 Bc * 4 * Hc);

    // ---- two small mamba mixers (L=1) ----
    const float* mx = x2;
    float* mouts[2] = {xm1, xm2};
    for (int m = 0; m < 2; m++) {
        small_mm_kernel<0><<<(Bc * 2 * DI2c + 255) / 256, 256, 0, stream>>>(
            mx, D2c, D2c, m_in_w[m], xz2, 2 * DI2c, Bc, nullptr);
        conv1_silu_kernel<<<(Bc * DI2c + 255) / 256, 256, 0, stream>>>(
            xz2, m_conv_w[m], m_conv_b[m], u2, Bc * DI2c);
        small_mm_kernel<0><<<(Bc * (R2c + 2 * NSc) + 255) / 256, 256, 0, stream>>>(
            u2, DI2c, DI2c, m_xproj_w[m], dbl2, R2c + 2 * NSc, Bc, nullptr);
        small_mm_kernel<1><<<(Bc * DI2c + 255) / 256, 256, 0, stream>>>(
            dbl2, R2c + 2 * NSc, R2c, m_dtproj_w[m], dt2, DI2c, Bc, m_dtproj_b[m]);
        scan1_kernel<<<(Bc * DI2c + 255) / 256, 256, 0, stream>>>(
            dt2, u2, dbl2, m_D[m], xz2, y2, Bc * DI2c);
        small_mm_kernel<0><<<(Bc * D2c + 255) / 256, 256, 0, stream>>>(
            y2, DI2c, DI2c, m_out_w[m], mouts[m], D2c, Bc, nullptr);
        mx = mouts[m];
    }

    // ---- classifier ----
    logits_kernel<<<1, 64, 0, stream>>>(xm2, fc_w, fc_b, out);
}